// Round 3
// baseline (611.288 us; speedup 1.0000x reference)
//
#include <hip/hip_runtime.h>

#define NSLOPE 0.2f

// ======================= CSR build (per-launch; ws is re-poisoned) ==========
__global__ void init_cnt_kernel(int* cnt, int n){
  int i = blockIdx.x*blockDim.x + threadIdx.x;
  if (i < n) cnt[i] = 1;                       // count the self-loop up front
}

__global__ void hist_kernel(const int* __restrict__ ei, int E, int* cnt){
  int e = blockIdx.x*blockDim.x + threadIdx.x;
  if (e < E) atomicAdd(&cnt[ei[E + e]], 1);    // dst row of edge_index
}

// single-block chunked Hillis-Steele exclusive scan over N counts
__global__ void scan_kernel(const int* __restrict__ cnt, int* __restrict__ rowptr,
                            int* __restrict__ cursor, int n){
  __shared__ int sdata[1024];
  __shared__ int run_s;
  int t = threadIdx.x;
  if (t == 0) run_s = 0;
  __syncthreads();
  for (int base = 0; base < n; base += 1024){
    int idx = base + t;
    int v = (idx < n) ? cnt[idx] : 0;
    sdata[t] = v;
    __syncthreads();
    for (int off = 1; off < 1024; off <<= 1){
      int x = (t >= off) ? sdata[t - off] : 0;
      __syncthreads();
      sdata[t] += x;
      __syncthreads();
    }
    int run = run_s;
    int excl = run + sdata[t] - v;
    if (idx < n){ rowptr[idx] = excl; cursor[idx] = excl; }
    __syncthreads();
    if (t == 1023) run_s = run + sdata[1023];
    __syncthreads();
  }
  if (t == 0) rowptr[n] = run_s;
}

__global__ void fill_kernel(const int* __restrict__ ei, int E, int n,
                            int* cursor, int* __restrict__ col){
  int i = blockIdx.x*blockDim.x + threadIdx.x;
  if (i < E){
    int s = ei[i], d = ei[E + i];
    int slot = atomicAdd(&cursor[d], 1);
    col[slot] = s;
  } else if (i < E + n){
    int v = i - E;                             // self loop (v -> v)
    int slot = atomicAdd(&cursor[v], 1);
    col[slot] = v;
  }
}

// ======================= fp32 tiled GEMM: C[M,Nc] = A[M,K] @ B[K,Nc] ========
#define BM 64
#define BN 64
#define BK 16
#define LDA (BM + 4)
#define LDB (BN + 4)
__global__ __launch_bounds__(256) void gemm_kernel(const float* __restrict__ A,
    const float* __restrict__ B, float* __restrict__ C, int M, int Nc, int K){
  __shared__ float As[BK][LDA];
  __shared__ float Bs[BK][LDB];
  int t  = threadIdx.x;
  int bm = blockIdx.x * BM;
  int bn = blockIdx.y * BN;
  int tx = t & 15, ty = t >> 4;
  int arow = t >> 2, ak = (t & 3) << 2;
  int bkr  = t >> 4, bnc = (t & 15) << 2;
  float acc[4][4] = {};
  for (int k0 = 0; k0 < K; k0 += BK){
    int grow = bm + arow;
    float4 av = make_float4(0.f,0.f,0.f,0.f);
    if (grow < M) av = *(const float4*)(A + (size_t)grow*K + k0 + ak);
    As[ak+0][arow] = av.x; As[ak+1][arow] = av.y;
    As[ak+2][arow] = av.z; As[ak+3][arow] = av.w;
    float4 bv = *(const float4*)(B + (size_t)(k0 + bkr)*Nc + bn + bnc);
    *(float4*)&Bs[bkr][bnc] = bv;
    __syncthreads();
#pragma unroll
    for (int k = 0; k < BK; k++){
      float a[4], b[4];
#pragma unroll
      for (int j = 0; j < 4; j++){ a[j] = As[k][ty*4 + j]; b[j] = Bs[k][tx*4 + j]; }
#pragma unroll
      for (int i = 0; i < 4; i++)
#pragma unroll
        for (int j = 0; j < 4; j++) acc[i][j] += a[i]*b[j];
    }
    __syncthreads();
  }
#pragma unroll
  for (int i = 0; i < 4; i++){
    int row = bm + ty*4 + i;
    if (row < M){
      float4 v = make_float4(acc[i][0], acc[i][1], acc[i][2], acc[i][3]);
      *(float4*)(C + (size_t)row*Nc + bn + tx*4) = v;
    }
  }
}

// ============== attention coefficients: al_s/al_d[n,h] = <h_row, a> =========
template<int H, int CH>
__global__ __launch_bounds__(128) void attn_coef_kernel(
    const float* __restrict__ Hm, const float* __restrict__ asrc,
    const float* __restrict__ adst, float* __restrict__ al_s,
    float* __restrict__ al_d){
  int b = blockIdx.x;                 // n*H + h
  int n = b / H, h = b % H;
  const float* row = Hm + (size_t)n*(H*CH) + (size_t)h*CH;
  int t = threadIdx.x;
  float ss = 0.f, sd = 0.f;
  for (int c = t; c < CH; c += 128){
    float v = row[c];
    ss += v * asrc[h*CH + c];
    sd += v * adst[h*CH + c];
  }
#pragma unroll
  for (int off = 32; off > 0; off >>= 1){
    ss += __shfl_down(ss, off);
    sd += __shfl_down(sd, off);
  }
  __shared__ float r0[2], r1[2];
  int wave = t >> 6, lane = t & 63;
  if (lane == 0){ r0[wave] = ss; r1[wave] = sd; }
  __syncthreads();
  if (t == 0){ al_s[b] = r0[0] + r0[1]; al_d[b] = r1[0] + r1[1]; }
}

// ========== per-dst softmax: one WAVE per node, shuffle-only (no barriers) ==
// writes unnormalized e per edge (alphaE[e][h]) and per-node denom[d][h].
template<int H>
__global__ __launch_bounds__(64) void alpha_kernel(
    const float* __restrict__ al_s, const float* __restrict__ al_d,
    const int* __restrict__ rowptr, const int* __restrict__ col,
    float* __restrict__ alphaE, float* __restrict__ denom){
  int d = blockIdx.x;
  int lane = threadIdx.x;              // 0..63
  int start = rowptr[d], end = rowptr[d + 1];

  float ald[H];
#pragma unroll
  for (int h = 0; h < H; h++) ald[h] = al_d[(size_t)d*H + h];

  // pass 1: per-head max
  float mx[H];
#pragma unroll
  for (int h = 0; h < H; h++) mx[h] = -1e30f;
  for (int e = start + lane; e < end; e += 64){
    int s = col[e];
#pragma unroll
    for (int h = 0; h < H; h++){
      float v = al_s[(size_t)s*H + h] + ald[h];
      v = (v > 0.f) ? v : NSLOPE * v;
      mx[h] = fmaxf(mx[h], v);
    }
  }
#pragma unroll
  for (int h = 0; h < H; h++)
#pragma unroll
    for (int off = 32; off > 0; off >>= 1)
      mx[h] = fmaxf(mx[h], __shfl_xor(mx[h], off));

  // pass 2: e = exp(logit - max); write e, reduce sums
  float sm[H] = {};
  for (int e = start + lane; e < end; e += 64){
    int s = col[e];
#pragma unroll
    for (int h = 0; h < H; h++){
      float v = al_s[(size_t)s*H + h] + ald[h];
      v = (v > 0.f) ? v : NSLOPE * v;
      float ev = __expf(v - mx[h]);
      alphaE[(size_t)e*H + h] = ev;
      sm[h] += ev;
    }
  }
#pragma unroll
  for (int h = 0; h < H; h++)
#pragma unroll
    for (int off = 32; off > 0; off >>= 1)
      sm[h] += __shfl_xor(sm[h], off);
  if (lane == 0){
#pragma unroll
    for (int h = 0; h < H; h++) denom[(size_t)d*H + h] = sm[h];
  }
}

// ====== weighted gather: out[d] = (Σ e[edge]*H[src]) / denom + bias =========
// one block of 128 threads per node; thread t owns channels 4t..4t+3 (float4).
template<int H, bool RELU>
__global__ __launch_bounds__(128) void aggregate_kernel(
    const float* __restrict__ Hm, const float* __restrict__ alphaE,
    const float* __restrict__ denom, const int* __restrict__ rowptr,
    const int* __restrict__ col, const float* __restrict__ bias,
    float* __restrict__ outF){
  constexpr int F4 = 128;              // 512 channels / 4
  __shared__ int   src_lds[64];
  __shared__ float a_lds[64 * H];

  int d = blockIdx.x;
  int t = threadIdx.x;
  int start = rowptr[d], end = rowptr[d + 1];
  const int hh = (t * H) >> 7;         // head of this thread's 4 channels
  const float4* __restrict__ Hm4 = (const float4*)Hm;

  float4 a0 = make_float4(0.f,0.f,0.f,0.f);
  float4 a1 = make_float4(0.f,0.f,0.f,0.f);
  float4 a2 = make_float4(0.f,0.f,0.f,0.f);
  float4 a3 = make_float4(0.f,0.f,0.f,0.f);

  for (int c0 = start; c0 < end; c0 += 64){
    int cnt = min(64, end - c0);
    if (t < cnt){
      src_lds[t] = col[c0 + t];
#pragma unroll
      for (int h = 0; h < H; h++)
        a_lds[t*H + h] = alphaE[(size_t)(c0 + t)*H + h];
    }
    __syncthreads();
    int i = 0;
    for (; i + 4 <= cnt; i += 4){
      int s0 = src_lds[i], s1 = src_lds[i+1], s2 = src_lds[i+2], s3 = src_lds[i+3];
      float e0 = a_lds[(i  )*H + hh], e1 = a_lds[(i+1)*H + hh];
      float e2 = a_lds[(i+2)*H + hh], e3 = a_lds[(i+3)*H + hh];
      float4 v0 = Hm4[(size_t)s0*F4 + t];
      float4 v1 = Hm4[(size_t)s1*F4 + t];
      float4 v2 = Hm4[(size_t)s2*F4 + t];
      float4 v3 = Hm4[(size_t)s3*F4 + t];
      a0.x += e0*v0.x; a0.y += e0*v0.y; a0.z += e0*v0.z; a0.w += e0*v0.w;
      a1.x += e1*v1.x; a1.y += e1*v1.y; a1.z += e1*v1.z; a1.w += e1*v1.w;
      a2.x += e2*v2.x; a2.y += e2*v2.y; a2.z += e2*v2.z; a2.w += e2*v2.w;
      a3.x += e3*v3.x; a3.y += e3*v3.y; a3.z += e3*v3.z; a3.w += e3*v3.w;
    }
    for (; i < cnt; i++){
      int s0 = src_lds[i];
      float e0 = a_lds[i*H + hh];
      float4 v0 = Hm4[(size_t)s0*F4 + t];
      a0.x += e0*v0.x; a0.y += e0*v0.y; a0.z += e0*v0.z; a0.w += e0*v0.w;
    }
    __syncthreads();
  }

  float4 acc;
  acc.x = (a0.x + a1.x) + (a2.x + a3.x);
  acc.y = (a0.y + a1.y) + (a2.y + a3.y);
  acc.z = (a0.z + a1.z) + (a2.z + a3.z);
  acc.w = (a0.w + a1.w) + (a2.w + a3.w);
  float inv = 1.f / denom[(size_t)d*H + hh];
  float4 bv = ((const float4*)bias)[t];
  float4 r;
  r.x = acc.x * inv + bv.x;
  r.y = acc.y * inv + bv.y;
  r.z = acc.z * inv + bv.z;
  r.w = acc.w * inv + bv.w;
  if (RELU){
    r.x = fmaxf(r.x, 0.f); r.y = fmaxf(r.y, 0.f);
    r.z = fmaxf(r.z, 0.f); r.w = fmaxf(r.w, 0.f);
  }
  ((float4*)outF)[(size_t)d*F4 + t] = r;
}

// =========================== launch =========================================
extern "C" void kernel_launch(void* const* d_in, const int* in_sizes, int n_in,
                              void* d_out, int out_size, void* d_ws, size_t ws_size,
                              hipStream_t stream){
  const float* x   = (const float*)d_in[0];
  const int*   ei  = (const int*)  d_in[1];
  const float* W1  = (const float*)d_in[2];
  const float* as1 = (const float*)d_in[3];
  const float* ad1 = (const float*)d_in[4];
  const float* b1  = (const float*)d_in[5];
  const float* W2  = (const float*)d_in[6];
  const float* as2 = (const float*)d_in[7];
  const float* ad2 = (const float*)d_in[8];
  const float* b2  = (const float*)d_in[9];
  const float* W3  = (const float*)d_in[10];
  const float* as3 = (const float*)d_in[11];
  const float* ad3 = (const float*)d_in[12];
  const float* b3  = (const float*)d_in[13];
  float* out = (float*)d_out;

  const int N = in_sizes[0] / 128;   // 10000
  const int E = in_sizes[1] / 2;     // 320000
  const int F = 512;
  const int Etot = E + N;

  // workspace carve-up
  float* Hmat  = (float*)d_ws;                  // N*512
  float* feat  = Hmat + (size_t)N*F;            // N*512
  float* al_s  = feat + (size_t)N*F;            // N*4
  float* al_d  = al_s + (size_t)N*4;            // N*4
  float* alphaE= al_d + (size_t)N*4;            // (E+N)*4
  float* denom = alphaE + (size_t)Etot*4;       // N*4
  int*   cnt    = (int*)(denom + (size_t)N*4);  // N
  int*   rowptr = cnt + N;                      // N+1
  int*   cursor = rowptr + N + 1;               // N
  int*   col    = cursor + N;                   // E+N

  // CSR by destination
  init_cnt_kernel<<<(N+255)/256, 256, 0, stream>>>(cnt, N);
  hist_kernel<<<(E+255)/256, 256, 0, stream>>>(ei, E, cnt);
  scan_kernel<<<1, 1024, 0, stream>>>(cnt, rowptr, cursor, N);
  fill_kernel<<<(E+N+255)/256, 256, 0, stream>>>(ei, E, N, cursor, col);

  dim3 ggrid((N + BM - 1)/BM, F/BN);

  // ---- layer 1: x[N,128] @ W1[128,512] ----
  gemm_kernel<<<ggrid, 256, 0, stream>>>(x, W1, Hmat, N, F, 128);
  attn_coef_kernel<4,128><<<N*4, 128, 0, stream>>>(Hmat, as1, ad1, al_s, al_d);
  alpha_kernel<4><<<N, 64, 0, stream>>>(al_s, al_d, rowptr, col, alphaE, denom);
  aggregate_kernel<4,true><<<N, 128, 0, stream>>>(Hmat, alphaE, denom, rowptr, col, b1, feat);

  // ---- layer 2: feat[N,512] @ W2[512,512] ----
  gemm_kernel<<<ggrid, 256, 0, stream>>>(feat, W2, Hmat, N, F, 512);
  attn_coef_kernel<4,128><<<N*4, 128, 0, stream>>>(Hmat, as2, ad2, al_s, al_d);
  alpha_kernel<4><<<N, 64, 0, stream>>>(al_s, al_d, rowptr, col, alphaE, denom);
  aggregate_kernel<4,true><<<N, 128, 0, stream>>>(Hmat, alphaE, denom, rowptr, col, b2, feat);

  // ---- layer 3: feat[N,512] @ W3[512,512], heads=1 ----
  gemm_kernel<<<ggrid, 256, 0, stream>>>(feat, W3, Hmat, N, F, 512);
  attn_coef_kernel<1,512><<<N, 128, 0, stream>>>(Hmat, as3, ad3, al_s, al_d);
  alpha_kernel<1><<<N, 64, 0, stream>>>(al_s, al_d, rowptr, col, alphaE, denom);
  aggregate_kernel<1,false><<<N, 128, 0, stream>>>(Hmat, alphaE, denom, rowptr, col, b3, out);
}

// Round 4
// 562.539 us; speedup vs baseline: 1.0867x; 1.0867x over previous
//
#include <hip/hip_runtime.h>

#define NSLOPE 0.2f

typedef __bf16 bf16x8 __attribute__((ext_vector_type(8)));
typedef float  f32x4  __attribute__((ext_vector_type(4)));

// ======================= CSR build (per-launch; ws is re-poisoned) ==========
__global__ void init_cnt_kernel(int* cnt, int n){
  int i = blockIdx.x*blockDim.x + threadIdx.x;
  if (i < n) cnt[i] = 1;                       // count the self-loop up front
}

__global__ void hist_kernel(const int* __restrict__ ei, int E, int* cnt){
  int e = blockIdx.x*blockDim.x + threadIdx.x;
  if (e < E) atomicAdd(&cnt[ei[E + e]], 1);    // dst row of edge_index
}

// single-block chunked Hillis-Steele exclusive scan over N counts
__global__ void scan_kernel(const int* __restrict__ cnt, int* __restrict__ rowptr,
                            int* __restrict__ cursor, int n){
  __shared__ int sdata[1024];
  __shared__ int run_s;
  int t = threadIdx.x;
  if (t == 0) run_s = 0;
  __syncthreads();
  for (int base = 0; base < n; base += 1024){
    int idx = base + t;
    int v = (idx < n) ? cnt[idx] : 0;
    sdata[t] = v;
    __syncthreads();
    for (int off = 1; off < 1024; off <<= 1){
      int x = (t >= off) ? sdata[t - off] : 0;
      __syncthreads();
      sdata[t] += x;
      __syncthreads();
    }
    int run = run_s;
    int excl = run + sdata[t] - v;
    if (idx < n){ rowptr[idx] = excl; cursor[idx] = excl; }
    __syncthreads();
    if (t == 1023) run_s = run + sdata[1023];
    __syncthreads();
  }
  if (t == 0) rowptr[n] = run_s;
}

__global__ void fill_kernel(const int* __restrict__ ei, int E, int n,
                            int* cursor, int* __restrict__ col){
  int i = blockIdx.x*blockDim.x + threadIdx.x;
  if (i < E){
    int s = ei[i], d = ei[E + i];
    int slot = atomicAdd(&cursor[d], 1);
    col[slot] = s;
  } else if (i < E + n){
    int v = i - E;                             // self loop (v -> v)
    int slot = atomicAdd(&cursor[v], 1);
    col[slot] = v;
  }
}

// ============ W [K][Nc] fp32 -> Bt_hi/Bt_lo [Nc][K] bf16 (split) ============
__global__ __launch_bounds__(256) void wsplit_kernel(
    const float* __restrict__ W, __bf16* __restrict__ Bthi,
    __bf16* __restrict__ Btlo, int K, int Nc){
  __shared__ float hi_s[32][33], lo_s[32][33];
  int tx = threadIdx.x & 31, ty = threadIdx.x >> 5;   // 32 x 8
  int k0 = blockIdx.x * 32, n0 = blockIdx.y * 32;
#pragma unroll
  for (int i = 0; i < 4; i++){
    int r = ty + i*8;
    float v = W[(size_t)(k0 + r)*Nc + n0 + tx];
    float h = (float)(__bf16)v;
    hi_s[r][tx] = h;
    lo_s[r][tx] = v - h;
  }
  __syncthreads();
#pragma unroll
  for (int i = 0; i < 4; i++){
    int n = ty + i*8;
    Bthi[(size_t)(n0 + n)*K + k0 + tx] = (__bf16)hi_s[tx][n];
    Btlo[(size_t)(n0 + n)*K + k0 + tx] = (__bf16)lo_s[tx][n];
  }
}

// ========== split-bf16 MFMA GEMM: C[M][Nc] = A[M][K] @ B[K][Nc] =============
// C = Ahi*Bhi + Ahi*Blo + Alo*Bhi (lo*lo dropped, ~2^-16 rel).
// 64(M) x 128(N) tile, BK=32, 256 thr = 4 waves; wave w owns n in [w*32,+32).
#define GBM 64
#define GBN 128
#define GBK 32
#define GLD 40   // LDS row stride (bf16 elems), 16B-aligned, breaks pow2
__global__ __launch_bounds__(256) void gemm_mfma(
    const float* __restrict__ A, const __bf16* __restrict__ Bthi,
    const __bf16* __restrict__ Btlo, float* __restrict__ C,
    int M, int Nc, int K){
  __shared__ __bf16 Ah[GBM][GLD], Al[GBM][GLD];
  __shared__ __bf16 Bh[GBN][GLD], Bl[GBN][GLD];
  int t  = threadIdx.x;
  int bm = blockIdx.x * GBM, bn = blockIdx.y * GBN;
  int lane = t & 63, w = t >> 6;
  int mm = lane & 15, q = lane >> 4;
  // staging coords
  int ar = t >> 2, ak = (t & 3) * 8;          // A: 64 rows x 32 k, 8 floats/thr
  int bnr = t & 127, bko = (t >> 7) * 16;     // B: 128 rows x 32 k, 16 bf16/thr

  f32x4 acc[4][2];
#pragma unroll
  for (int i = 0; i < 4; i++)
#pragma unroll
    for (int j = 0; j < 2; j++)
#pragma unroll
      for (int r = 0; r < 4; r++) acc[i][j][r] = 0.f;

  for (int k0 = 0; k0 < K; k0 += GBK){
    // ---- stage A (fp32 -> hi/lo bf16) ----
    int grow = bm + ar;
    float4 f0 = make_float4(0.f,0.f,0.f,0.f);
    float4 f1 = make_float4(0.f,0.f,0.f,0.f);
    if (grow < M){
      const float* ap = A + (size_t)grow*K + k0 + ak;
      f0 = *(const float4*)ap;
      f1 = *(const float4*)(ap + 4);
    }
    float ff[8] = {f0.x,f0.y,f0.z,f0.w,f1.x,f1.y,f1.z,f1.w};
    bf16x8 vh, vl;
#pragma unroll
    for (int u = 0; u < 8; u++){
      __bf16 h = (__bf16)ff[u];
      vh[u] = h;
      vl[u] = (__bf16)(ff[u] - (float)h);
    }
    *(bf16x8*)&Ah[ar][ak] = vh;
    *(bf16x8*)&Al[ar][ak] = vl;
    // ---- stage B (pre-split bf16, [n][k] layout) ----
    const __bf16* ph = Bthi + (size_t)(bn + bnr)*K + k0 + bko;
    const __bf16* pl = Btlo + (size_t)(bn + bnr)*K + k0 + bko;
    *(bf16x8*)&Bh[bnr][bko]     = *(const bf16x8*)ph;
    *(bf16x8*)&Bh[bnr][bko + 8] = *(const bf16x8*)(ph + 8);
    *(bf16x8*)&Bl[bnr][bko]     = *(const bf16x8*)pl;
    *(bf16x8*)&Bl[bnr][bko + 8] = *(const bf16x8*)(pl + 8);
    __syncthreads();
    // ---- fragments ----
    bf16x8 a_h[4], a_l[4], b_h[2], b_l[2];
#pragma unroll
    for (int i = 0; i < 4; i++){
      a_h[i] = *(bf16x8*)&Ah[i*16 + mm][q*8];
      a_l[i] = *(bf16x8*)&Al[i*16 + mm][q*8];
    }
#pragma unroll
    for (int j = 0; j < 2; j++){
      b_h[j] = *(bf16x8*)&Bh[w*32 + j*16 + mm][q*8];
      b_l[j] = *(bf16x8*)&Bl[w*32 + j*16 + mm][q*8];
    }
#pragma unroll
    for (int i = 0; i < 4; i++)
#pragma unroll
      for (int j = 0; j < 2; j++){
        acc[i][j] = __builtin_amdgcn_mfma_f32_16x16x32_bf16(a_h[i], b_h[j], acc[i][j], 0, 0, 0);
        acc[i][j] = __builtin_amdgcn_mfma_f32_16x16x32_bf16(a_h[i], b_l[j], acc[i][j], 0, 0, 0);
        acc[i][j] = __builtin_amdgcn_mfma_f32_16x16x32_bf16(a_l[i], b_h[j], acc[i][j], 0, 0, 0);
      }
    __syncthreads();
  }
  // ---- store C: reg r -> row = q*4 + r, col = mm ----
#pragma unroll
  for (int i = 0; i < 4; i++){
#pragma unroll
    for (int j = 0; j < 2; j++){
      int colc = bn + w*32 + j*16 + mm;
#pragma unroll
      for (int r = 0; r < 4; r++){
        int row = bm + i*16 + q*4 + r;
        if (row < M) C[(size_t)row*Nc + colc] = acc[i][j][r];
      }
    }
  }
}

// ============== attention coefficients: al_s/al_d[n,h] = <h_row, a> =========
template<int H, int CH>
__global__ __launch_bounds__(128) void attn_coef_kernel(
    const float* __restrict__ Hm, const float* __restrict__ asrc,
    const float* __restrict__ adst, float* __restrict__ al_s,
    float* __restrict__ al_d){
  int b = blockIdx.x;                 // n*H + h
  int n = b / H, h = b % H;
  const float* row = Hm + (size_t)n*(H*CH) + (size_t)h*CH;
  int t = threadIdx.x;
  float ss = 0.f, sd = 0.f;
  for (int c = t; c < CH; c += 128){
    float v = row[c];
    ss += v * asrc[h*CH + c];
    sd += v * adst[h*CH + c];
  }
#pragma unroll
  for (int off = 32; off > 0; off >>= 1){
    ss += __shfl_down(ss, off);
    sd += __shfl_down(sd, off);
  }
  __shared__ float r0[2], r1[2];
  int wave = t >> 6, lane = t & 63;
  if (lane == 0){ r0[wave] = ss; r1[wave] = sd; }
  __syncthreads();
  if (t == 0){ al_s[b] = r0[0] + r0[1]; al_d[b] = r1[0] + r1[1]; }
}

// ========== per-dst softmax: one WAVE per node, shuffle-only ================
template<int H>
__global__ __launch_bounds__(64) void alpha_kernel(
    const float* __restrict__ al_s, const float* __restrict__ al_d,
    const int* __restrict__ rowptr, const int* __restrict__ col,
    float* __restrict__ alphaE, float* __restrict__ denom){
  int d = blockIdx.x;
  int lane = threadIdx.x;              // 0..63
  int start = rowptr[d], end = rowptr[d + 1];

  float ald[H];
#pragma unroll
  for (int h = 0; h < H; h++) ald[h] = al_d[(size_t)d*H + h];

  float mx[H];
#pragma unroll
  for (int h = 0; h < H; h++) mx[h] = -1e30f;
  for (int e = start + lane; e < end; e += 64){
    int s = col[e];
#pragma unroll
    for (int h = 0; h < H; h++){
      float v = al_s[(size_t)s*H + h] + ald[h];
      v = (v > 0.f) ? v : NSLOPE * v;
      mx[h] = fmaxf(mx[h], v);
    }
  }
#pragma unroll
  for (int h = 0; h < H; h++)
#pragma unroll
    for (int off = 32; off > 0; off >>= 1)
      mx[h] = fmaxf(mx[h], __shfl_xor(mx[h], off));

  float sm[H] = {};
  for (int e = start + lane; e < end; e += 64){
    int s = col[e];
#pragma unroll
    for (int h = 0; h < H; h++){
      float v = al_s[(size_t)s*H + h] + ald[h];
      v = (v > 0.f) ? v : NSLOPE * v;
      float ev = __expf(v - mx[h]);
      alphaE[(size_t)e*H + h] = ev;
      sm[h] += ev;
    }
  }
#pragma unroll
  for (int h = 0; h < H; h++)
#pragma unroll
    for (int off = 32; off > 0; off >>= 1)
      sm[h] += __shfl_xor(sm[h], off);
  if (lane == 0){
#pragma unroll
    for (int h = 0; h < H; h++) denom[(size_t)d*H + h] = sm[h];
  }
}

// ====== weighted gather: out[d] = (Σ e[edge]*H[src]) / denom + bias =========
template<int H, bool RELU>
__global__ __launch_bounds__(128) void aggregate_kernel(
    const float* __restrict__ Hm, const float* __restrict__ alphaE,
    const float* __restrict__ denom, const int* __restrict__ rowptr,
    const int* __restrict__ col, const float* __restrict__ bias,
    float* __restrict__ outF){
  constexpr int F4 = 128;              // 512 channels / 4
  __shared__ int   src_lds[64];
  __shared__ float a_lds[64 * H];

  int d = blockIdx.x;
  int t = threadIdx.x;
  int start = rowptr[d], end = rowptr[d + 1];
  const int hh = (t * H) >> 7;         // head of this thread's 4 channels
  const float4* __restrict__ Hm4 = (const float4*)Hm;

  float4 a0 = make_float4(0.f,0.f,0.f,0.f);
  float4 a1 = make_float4(0.f,0.f,0.f,0.f);
  float4 a2 = make_float4(0.f,0.f,0.f,0.f);
  float4 a3 = make_float4(0.f,0.f,0.f,0.f);

  for (int c0 = start; c0 < end; c0 += 64){
    int cnt = min(64, end - c0);
    if (t < cnt){
      src_lds[t] = col[c0 + t];
#pragma unroll
      for (int h = 0; h < H; h++)
        a_lds[t*H + h] = alphaE[(size_t)(c0 + t)*H + h];
    }
    __syncthreads();
    int i = 0;
    for (; i + 4 <= cnt; i += 4){
      int s0 = src_lds[i], s1 = src_lds[i+1], s2 = src_lds[i+2], s3 = src_lds[i+3];
      float e0 = a_lds[(i  )*H + hh], e1 = a_lds[(i+1)*H + hh];
      float e2 = a_lds[(i+2)*H + hh], e3 = a_lds[(i+3)*H + hh];
      float4 v0 = Hm4[(size_t)s0*F4 + t];
      float4 v1 = Hm4[(size_t)s1*F4 + t];
      float4 v2 = Hm4[(size_t)s2*F4 + t];
      float4 v3 = Hm4[(size_t)s3*F4 + t];
      a0.x += e0*v0.x; a0.y += e0*v0.y; a0.z += e0*v0.z; a0.w += e0*v0.w;
      a1.x += e1*v1.x; a1.y += e1*v1.y; a1.z += e1*v1.z; a1.w += e1*v1.w;
      a2.x += e2*v2.x; a2.y += e2*v2.y; a2.z += e2*v2.z; a2.w += e2*v2.w;
      a3.x += e3*v3.x; a3.y += e3*v3.y; a3.z += e3*v3.z; a3.w += e3*v3.w;
    }
    for (; i < cnt; i++){
      int s0 = src_lds[i];
      float e0 = a_lds[i*H + hh];
      float4 v0 = Hm4[(size_t)s0*F4 + t];
      a0.x += e0*v0.x; a0.y += e0*v0.y; a0.z += e0*v0.z; a0.w += e0*v0.w;
    }
    __syncthreads();
  }

  float4 acc;
  acc.x = (a0.x + a1.x) + (a2.x + a3.x);
  acc.y = (a0.y + a1.y) + (a2.y + a3.y);
  acc.z = (a0.z + a1.z) + (a2.z + a3.z);
  acc.w = (a0.w + a1.w) + (a2.w + a3.w);
  float inv = 1.f / denom[(size_t)d*H + hh];
  float4 bv = ((const float4*)bias)[t];
  float4 r;
  r.x = acc.x * inv + bv.x;
  r.y = acc.y * inv + bv.y;
  r.z = acc.z * inv + bv.z;
  r.w = acc.w * inv + bv.w;
  if (RELU){
    r.x = fmaxf(r.x, 0.f); r.y = fmaxf(r.y, 0.f);
    r.z = fmaxf(r.z, 0.f); r.w = fmaxf(r.w, 0.f);
  }
  ((float4*)outF)[(size_t)d*F4 + t] = r;
}

// =========================== launch =========================================
extern "C" void kernel_launch(void* const* d_in, const int* in_sizes, int n_in,
                              void* d_out, int out_size, void* d_ws, size_t ws_size,
                              hipStream_t stream){
  const float* x   = (const float*)d_in[0];
  const int*   ei  = (const int*)  d_in[1];
  const float* W1  = (const float*)d_in[2];
  const float* as1 = (const float*)d_in[3];
  const float* ad1 = (const float*)d_in[4];
  const float* b1  = (const float*)d_in[5];
  const float* W2  = (const float*)d_in[6];
  const float* as2 = (const float*)d_in[7];
  const float* ad2 = (const float*)d_in[8];
  const float* b2  = (const float*)d_in[9];
  const float* W3  = (const float*)d_in[10];
  const float* as3 = (const float*)d_in[11];
  const float* ad3 = (const float*)d_in[12];
  const float* b3  = (const float*)d_in[13];
  float* out = (float*)d_out;

  const int N = in_sizes[0] / 128;   // 10000
  const int E = in_sizes[1] / 2;     // 320000
  const int F = 512;
  const int Etot = E + N;

  // workspace carve-up
  float* Hmat  = (float*)d_ws;                  // N*512
  float* feat  = Hmat + (size_t)N*F;            // N*512
  float* al_s  = feat + (size_t)N*F;            // N*4
  float* al_d  = al_s + (size_t)N*4;            // N*4
  float* alphaE= al_d + (size_t)N*4;            // (E+N)*4
  float* denom = alphaE + (size_t)Etot*4;       // N*4
  int*   cnt    = (int*)(denom + (size_t)N*4);  // N
  int*   rowptr = cnt + N;                      // N+1
  int*   cursor = rowptr + N + 1;               // N
  int*   col    = cursor + N;                   // E+N
  uintptr_t p  = (uintptr_t)(col + Etot);
  p = (p + 15) & ~(uintptr_t)15;
  __bf16* Bth = (__bf16*)p;                     // 512*512 bf16
  __bf16* Btl = Bth + 512*512;                  // 512*512 bf16

  // CSR by destination
  init_cnt_kernel<<<(N+255)/256, 256, 0, stream>>>(cnt, N);
  hist_kernel<<<(E+255)/256, 256, 0, stream>>>(ei, E, cnt);
  scan_kernel<<<1, 1024, 0, stream>>>(cnt, rowptr, cursor, N);
  fill_kernel<<<(E+N+255)/256, 256, 0, stream>>>(ei, E, N, cursor, col);

  dim3 ggrid((N + GBM - 1)/GBM, F/GBN);

  // ---- layer 1: x[N,128] @ W1[128,512] ----
  wsplit_kernel<<<dim3(128/32, F/32), 256, 0, stream>>>(W1, Bth, Btl, 128, F);
  gemm_mfma<<<ggrid, 256, 0, stream>>>(x, Bth, Btl, Hmat, N, F, 128);
  attn_coef_kernel<4,128><<<N*4, 128, 0, stream>>>(Hmat, as1, ad1, al_s, al_d);
  alpha_kernel<4><<<N, 64, 0, stream>>>(al_s, al_d, rowptr, col, alphaE, denom);
  aggregate_kernel<4,true><<<N, 128, 0, stream>>>(Hmat, alphaE, denom, rowptr, col, b1, feat);

  // ---- layer 2: feat[N,512] @ W2[512,512] ----
  wsplit_kernel<<<dim3(F/32, F/32), 256, 0, stream>>>(W2, Bth, Btl, F, F);
  gemm_mfma<<<ggrid, 256, 0, stream>>>(feat, Bth, Btl, Hmat, N, F, F);
  attn_coef_kernel<4,128><<<N*4, 128, 0, stream>>>(Hmat, as2, ad2, al_s, al_d);
  alpha_kernel<4><<<N, 64, 0, stream>>>(al_s, al_d, rowptr, col, alphaE, denom);
  aggregate_kernel<4,true><<<N, 128, 0, stream>>>(Hmat, alphaE, denom, rowptr, col, b2, feat);

  // ---- layer 3: feat[N,512] @ W3[512,512], heads=1 ----
  wsplit_kernel<<<dim3(F/32, F/32), 256, 0, stream>>>(W3, Bth, Btl, F, F);
  gemm_mfma<<<ggrid, 256, 0, stream>>>(feat, Bth, Btl, Hmat, N, F, F);
  attn_coef_kernel<1,512><<<N, 128, 0, stream>>>(Hmat, as3, ad3, al_s, al_d);
  alpha_kernel<1><<<N, 64, 0, stream>>>(al_s, al_d, rowptr, col, alphaE, denom);
  aggregate_kernel<1,false><<<N, 128, 0, stream>>>(Hmat, alphaE, denom, rowptr, col, b3, out);
}

// Round 5
// 431.395 us; speedup vs baseline: 1.4170x; 1.3040x over previous
//
#include <hip/hip_runtime.h>

#define NSLOPE 0.2f

typedef __bf16 bf16x8 __attribute__((ext_vector_type(8)));
typedef float  f32x4  __attribute__((ext_vector_type(4)));

// ======================= CSR build (per-launch; ws is re-poisoned) ==========
__global__ void init_cnt_kernel(int* cnt, int n){
  int i = blockIdx.x*blockDim.x + threadIdx.x;
  if (i < n) cnt[i] = 1;                       // count the self-loop up front
}

__global__ void hist_kernel(const int* __restrict__ ei, int E, int* cnt){
  int e = blockIdx.x*blockDim.x + threadIdx.x;
  if (e < E) atomicAdd(&cnt[ei[E + e]], 1);    // dst row of edge_index
}

// single-block chunked Hillis-Steele exclusive scan over N counts
__global__ void scan_kernel(const int* __restrict__ cnt, int* __restrict__ rowptr,
                            int* __restrict__ cursor, int n){
  __shared__ int sdata[1024];
  __shared__ int run_s;
  int t = threadIdx.x;
  if (t == 0) run_s = 0;
  __syncthreads();
  for (int base = 0; base < n; base += 1024){
    int idx = base + t;
    int v = (idx < n) ? cnt[idx] : 0;
    sdata[t] = v;
    __syncthreads();
    for (int off = 1; off < 1024; off <<= 1){
      int x = (t >= off) ? sdata[t - off] : 0;
      __syncthreads();
      sdata[t] += x;
      __syncthreads();
    }
    int run = run_s;
    int excl = run + sdata[t] - v;
    if (idx < n){ rowptr[idx] = excl; cursor[idx] = excl; }
    __syncthreads();
    if (t == 1023) run_s = run + sdata[1023];
    __syncthreads();
  }
  if (t == 0) rowptr[n] = run_s;
}

__global__ void fill_kernel(const int* __restrict__ ei, int E, int n,
                            int* cursor, int* __restrict__ col){
  int i = blockIdx.x*blockDim.x + threadIdx.x;
  if (i < E){
    int s = ei[i], d = ei[E + i];
    int slot = atomicAdd(&cursor[d], 1);
    col[slot] = s;
  } else if (i < E + n){
    int v = i - E;                             // self loop (v -> v)
    int slot = atomicAdd(&cursor[v], 1);
    col[slot] = v;
  }
}

// ============ W [K][Nc] fp32 -> Bt_hi/Bt_lo [Nc][K] bf16 (split) ============
__global__ __launch_bounds__(256) void wsplit_kernel(
    const float* __restrict__ W, __bf16* __restrict__ Bthi,
    __bf16* __restrict__ Btlo, int K, int Nc){
  __shared__ float hi_s[32][33], lo_s[32][33];
  int tx = threadIdx.x & 31, ty = threadIdx.x >> 5;   // 32 x 8
  int k0 = blockIdx.x * 32, n0 = blockIdx.y * 32;
#pragma unroll
  for (int i = 0; i < 4; i++){
    int r = ty + i*8;
    float v = W[(size_t)(k0 + r)*Nc + n0 + tx];
    float h = (float)(__bf16)v;
    hi_s[r][tx] = h;
    lo_s[r][tx] = v - h;
  }
  __syncthreads();
#pragma unroll
  for (int i = 0; i < 4; i++){
    int n = ty + i*8;
    Bthi[(size_t)(n0 + n)*K + k0 + tx] = (__bf16)hi_s[tx][n];
    Btlo[(size_t)(n0 + n)*K + k0 + tx] = (__bf16)lo_s[tx][n];
  }
}

// ========== split-bf16 MFMA GEMM: C[M][Nc] = A[M][K] @ B[K][Nc] =============
// C = Ahi*Bhi + Ahi*Blo + Alo*Bhi (lo*lo dropped, ~2^-16 rel).
#define GBM 64
#define GBN 128
#define GBK 32
#define GLD 40   // LDS row stride (bf16 elems), 16B-aligned, breaks pow2
__global__ __launch_bounds__(256) void gemm_mfma(
    const float* __restrict__ A, const __bf16* __restrict__ Bthi,
    const __bf16* __restrict__ Btlo, float* __restrict__ C,
    int M, int Nc, int K){
  __shared__ __bf16 Ah[GBM][GLD], Al[GBM][GLD];
  __shared__ __bf16 Bh[GBN][GLD], Bl[GBN][GLD];
  int t  = threadIdx.x;
  int bm = blockIdx.x * GBM, bn = blockIdx.y * GBN;
  int lane = t & 63, w = t >> 6;
  int mm = lane & 15, q = lane >> 4;
  int ar = t >> 2, ak = (t & 3) * 8;          // A: 64 rows x 32 k, 8 floats/thr
  int bnr = t & 127, bko = (t >> 7) * 16;     // B: 128 rows x 32 k, 16 bf16/thr

  f32x4 acc[4][2];
#pragma unroll
  for (int i = 0; i < 4; i++)
#pragma unroll
    for (int j = 0; j < 2; j++)
#pragma unroll
      for (int r = 0; r < 4; r++) acc[i][j][r] = 0.f;

  for (int k0 = 0; k0 < K; k0 += GBK){
    int grow = bm + ar;
    float4 f0 = make_float4(0.f,0.f,0.f,0.f);
    float4 f1 = make_float4(0.f,0.f,0.f,0.f);
    if (grow < M){
      const float* ap = A + (size_t)grow*K + k0 + ak;
      f0 = *(const float4*)ap;
      f1 = *(const float4*)(ap + 4);
    }
    float ff[8] = {f0.x,f0.y,f0.z,f0.w,f1.x,f1.y,f1.z,f1.w};
    bf16x8 vh, vl;
#pragma unroll
    for (int u = 0; u < 8; u++){
      __bf16 h = (__bf16)ff[u];
      vh[u] = h;
      vl[u] = (__bf16)(ff[u] - (float)h);
    }
    *(bf16x8*)&Ah[ar][ak] = vh;
    *(bf16x8*)&Al[ar][ak] = vl;
    const __bf16* ph = Bthi + (size_t)(bn + bnr)*K + k0 + bko;
    const __bf16* pl = Btlo + (size_t)(bn + bnr)*K + k0 + bko;
    *(bf16x8*)&Bh[bnr][bko]     = *(const bf16x8*)ph;
    *(bf16x8*)&Bh[bnr][bko + 8] = *(const bf16x8*)(ph + 8);
    *(bf16x8*)&Bl[bnr][bko]     = *(const bf16x8*)pl;
    *(bf16x8*)&Bl[bnr][bko + 8] = *(const bf16x8*)(pl + 8);
    __syncthreads();
    bf16x8 a_h[4], a_l[4], b_h[2], b_l[2];
#pragma unroll
    for (int i = 0; i < 4; i++){
      a_h[i] = *(bf16x8*)&Ah[i*16 + mm][q*8];
      a_l[i] = *(bf16x8*)&Al[i*16 + mm][q*8];
    }
#pragma unroll
    for (int j = 0; j < 2; j++){
      b_h[j] = *(bf16x8*)&Bh[w*32 + j*16 + mm][q*8];
      b_l[j] = *(bf16x8*)&Bl[w*32 + j*16 + mm][q*8];
    }
#pragma unroll
    for (int i = 0; i < 4; i++)
#pragma unroll
      for (int j = 0; j < 2; j++){
        acc[i][j] = __builtin_amdgcn_mfma_f32_16x16x32_bf16(a_h[i], b_h[j], acc[i][j], 0, 0, 0);
        acc[i][j] = __builtin_amdgcn_mfma_f32_16x16x32_bf16(a_h[i], b_l[j], acc[i][j], 0, 0, 0);
        acc[i][j] = __builtin_amdgcn_mfma_f32_16x16x32_bf16(a_l[i], b_h[j], acc[i][j], 0, 0, 0);
      }
    __syncthreads();
  }
#pragma unroll
  for (int i = 0; i < 4; i++){
#pragma unroll
    for (int j = 0; j < 2; j++){
      int colc = bn + w*32 + j*16 + mm;
#pragma unroll
      for (int r = 0; r < 4; r++){
        int row = bm + i*16 + q*4 + r;
        if (row < M) C[(size_t)row*Nc + colc] = acc[i][j][r];
      }
    }
  }
}

// ===== attention coefficients + bf16 copy of H for the gather ==============
template<int H, int CH>
__global__ __launch_bounds__(128) void attn_coef_kernel(
    const float* __restrict__ Hm, const float* __restrict__ asrc,
    const float* __restrict__ adst, float* __restrict__ al_s,
    float* __restrict__ al_d, __bf16* __restrict__ Hb){
  int b = blockIdx.x;                 // n*H + h
  int n = b / H, h = b % H;
  const float* row = Hm + (size_t)n*(H*CH) + (size_t)h*CH;
  int t = threadIdx.x;
  float ss = 0.f, sd = 0.f;
  for (int c = t; c < CH; c += 128){
    float v = row[c];
    Hb[(size_t)b*CH + c] = (__bf16)v;   // same flat layout as Hm
    ss += v * asrc[h*CH + c];
    sd += v * adst[h*CH + c];
  }
#pragma unroll
  for (int off = 32; off > 0; off >>= 1){
    ss += __shfl_down(ss, off);
    sd += __shfl_down(sd, off);
  }
  __shared__ float r0[2], r1[2];
  int wave = t >> 6, lane = t & 63;
  if (lane == 0){ r0[wave] = ss; r1[wave] = sd; }
  __syncthreads();
  if (t == 0){ al_s[b] = r0[0] + r0[1]; al_d[b] = r1[0] + r1[1]; }
}

// ========== per-dst softmax: one WAVE per node, shuffle-only ================
template<int H>
__global__ __launch_bounds__(64) void alpha_kernel(
    const float* __restrict__ al_s, const float* __restrict__ al_d,
    const int* __restrict__ rowptr, const int* __restrict__ col,
    float* __restrict__ alphaE, float* __restrict__ denom){
  int d = blockIdx.x;
  int lane = threadIdx.x;              // 0..63
  int start = rowptr[d], end = rowptr[d + 1];

  float ald[H];
#pragma unroll
  for (int h = 0; h < H; h++) ald[h] = al_d[(size_t)d*H + h];

  float mx[H];
#pragma unroll
  for (int h = 0; h < H; h++) mx[h] = -1e30f;
  for (int e = start + lane; e < end; e += 64){
    int s = col[e];
#pragma unroll
    for (int h = 0; h < H; h++){
      float v = al_s[(size_t)s*H + h] + ald[h];
      v = (v > 0.f) ? v : NSLOPE * v;
      mx[h] = fmaxf(mx[h], v);
    }
  }
#pragma unroll
  for (int h = 0; h < H; h++)
#pragma unroll
    for (int off = 32; off > 0; off >>= 1)
      mx[h] = fmaxf(mx[h], __shfl_xor(mx[h], off));

  float sm[H] = {};
  for (int e = start + lane; e < end; e += 64){
    int s = col[e];
#pragma unroll
    for (int h = 0; h < H; h++){
      float v = al_s[(size_t)s*H + h] + ald[h];
      v = (v > 0.f) ? v : NSLOPE * v;
      float ev = __expf(v - mx[h]);
      alphaE[(size_t)e*H + h] = ev;
      sm[h] += ev;
    }
  }
#pragma unroll
  for (int h = 0; h < H; h++)
#pragma unroll
    for (int off = 32; off > 0; off >>= 1)
      sm[h] += __shfl_xor(sm[h], off);
  if (lane == 0){
#pragma unroll
    for (int h = 0; h < H; h++) denom[(size_t)d*H + h] = sm[h];
  }
}

// ====== weighted gather from bf16 rows: out[d] = (Σ e*Hb[src])/denom + bias =
// 128 thr = 2 edge-subgroups x 64 lanes; lane owns 8 contiguous channels.
template<int H, bool RELU>
__global__ __launch_bounds__(128) void aggregate_kernel(
    const __bf16* __restrict__ Hb, const float* __restrict__ alphaE,
    const float* __restrict__ denom, const int* __restrict__ rowptr,
    const int* __restrict__ col, const float* __restrict__ bias,
    float* __restrict__ outF){
  __shared__ int   src_lds[64];
  __shared__ float a_lds[64 * H];
  __shared__ float part[512];

  int d = blockIdx.x;
  int t = threadIdx.x;
  int g = t >> 6, lane = t & 63;
  int start = rowptr[d], end = rowptr[d + 1];
  const int hh = (lane * H) >> 6;              // head of lane's 8 channels
  const bf16x8* __restrict__ Hb8 = (const bf16x8*)Hb;   // row stride = 64

  float a0[8] = {};
  float a1[8] = {};
  for (int c0 = start; c0 < end; c0 += 64){
    int cnt = min(64, end - c0);
    if (t < cnt){
      src_lds[t] = col[c0 + t];
#pragma unroll
      for (int h = 0; h < H; h++)
        a_lds[t*H + h] = alphaE[(size_t)(c0 + t)*H + h];
    }
    __syncthreads();
    int i = g;
    for (; i + 2 < cnt; i += 4){
      int s0 = src_lds[i], s1 = src_lds[i + 2];
      float e0 = a_lds[i*H + hh], e1 = a_lds[(i + 2)*H + hh];
      bf16x8 v0 = Hb8[(size_t)s0*64 + lane];
      bf16x8 v1 = Hb8[(size_t)s1*64 + lane];
#pragma unroll
      for (int u = 0; u < 8; u++){
        a0[u] += e0 * (float)v0[u];
        a1[u] += e1 * (float)v1[u];
      }
    }
    for (; i < cnt; i += 2){
      int s0 = src_lds[i];
      float e0 = a_lds[i*H + hh];
      bf16x8 v0 = Hb8[(size_t)s0*64 + lane];
#pragma unroll
      for (int u = 0; u < 8; u++) a0[u] += e0 * (float)v0[u];
    }
    __syncthreads();
  }

  if (g == 1){
#pragma unroll
    for (int u = 0; u < 8; u++) part[lane*8 + u] = a0[u] + a1[u];
  }
  __syncthreads();
  if (g == 0){
    float inv = 1.f / denom[(size_t)d*H + hh];
    float r[8];
#pragma unroll
    for (int u = 0; u < 8; u++){
      float v = (a0[u] + a1[u] + part[lane*8 + u]) * inv + bias[lane*8 + u];
      if (RELU) v = fmaxf(v, 0.f);
      r[u] = v;
    }
    float4* op = (float4*)(outF + (size_t)d*512 + lane*8);
    op[0] = make_float4(r[0], r[1], r[2], r[3]);
    op[1] = make_float4(r[4], r[5], r[6], r[7]);
  }
}

// =========================== launch =========================================
extern "C" void kernel_launch(void* const* d_in, const int* in_sizes, int n_in,
                              void* d_out, int out_size, void* d_ws, size_t ws_size,
                              hipStream_t stream){
  const float* x   = (const float*)d_in[0];
  const int*   ei  = (const int*)  d_in[1];
  const float* W1  = (const float*)d_in[2];
  const float* as1 = (const float*)d_in[3];
  const float* ad1 = (const float*)d_in[4];
  const float* b1  = (const float*)d_in[5];
  const float* W2  = (const float*)d_in[6];
  const float* as2 = (const float*)d_in[7];
  const float* ad2 = (const float*)d_in[8];
  const float* b2  = (const float*)d_in[9];
  const float* W3  = (const float*)d_in[10];
  const float* as3 = (const float*)d_in[11];
  const float* ad3 = (const float*)d_in[12];
  const float* b3  = (const float*)d_in[13];
  float* out = (float*)d_out;

  const int N = in_sizes[0] / 128;   // 10000
  const int E = in_sizes[1] / 2;     // 320000
  const int F = 512;
  const int Etot = E + N;

  // workspace carve-up
  float* Hmat  = (float*)d_ws;                  // N*512
  float* feat  = Hmat + (size_t)N*F;            // N*512
  float* al_s  = feat + (size_t)N*F;            // N*4
  float* al_d  = al_s + (size_t)N*4;            // N*4
  float* alphaE= al_d + (size_t)N*4;            // (E+N)*4
  float* denom = alphaE + (size_t)Etot*4;       // N*4
  int*   cnt    = (int*)(denom + (size_t)N*4);  // N
  int*   rowptr = cnt + N;                      // N+1
  int*   cursor = rowptr + N + 1;               // N
  int*   col    = cursor + N;                   // E+N
  uintptr_t p  = (uintptr_t)(col + Etot);
  p = (p + 15) & ~(uintptr_t)15;
  __bf16* Bth = (__bf16*)p;                     // 512*512 bf16
  __bf16* Btl = Bth + 512*512;                  // 512*512 bf16
  __bf16* Hb  = Btl + 512*512;                  // N*512 bf16 (gather copy)

  // CSR by destination
  init_cnt_kernel<<<(N+255)/256, 256, 0, stream>>>(cnt, N);
  hist_kernel<<<(E+255)/256, 256, 0, stream>>>(ei, E, cnt);
  scan_kernel<<<1, 1024, 0, stream>>>(cnt, rowptr, cursor, N);
  fill_kernel<<<(E+N+255)/256, 256, 0, stream>>>(ei, E, N, cursor, col);

  dim3 ggrid((N + GBM - 1)/GBM, F/GBN);

  // ---- layer 1: x[N,128] @ W1[128,512] ----
  wsplit_kernel<<<dim3(128/32, F/32), 256, 0, stream>>>(W1, Bth, Btl, 128, F);
  gemm_mfma<<<ggrid, 256, 0, stream>>>(x, Bth, Btl, Hmat, N, F, 128);
  attn_coef_kernel<4,128><<<N*4, 128, 0, stream>>>(Hmat, as1, ad1, al_s, al_d, Hb);
  alpha_kernel<4><<<N, 64, 0, stream>>>(al_s, al_d, rowptr, col, alphaE, denom);
  aggregate_kernel<4,true><<<N, 128, 0, stream>>>(Hb, alphaE, denom, rowptr, col, b1, feat);

  // ---- layer 2: feat[N,512] @ W2[512,512] ----
  wsplit_kernel<<<dim3(F/32, F/32), 256, 0, stream>>>(W2, Bth, Btl, F, F);
  gemm_mfma<<<ggrid, 256, 0, stream>>>(feat, Bth, Btl, Hmat, N, F, F);
  attn_coef_kernel<4,128><<<N*4, 128, 0, stream>>>(Hmat, as2, ad2, al_s, al_d, Hb);
  alpha_kernel<4><<<N, 64, 0, stream>>>(al_s, al_d, rowptr, col, alphaE, denom);
  aggregate_kernel<4,true><<<N, 128, 0, stream>>>(Hb, alphaE, denom, rowptr, col, b2, feat);

  // ---- layer 3: feat[N,512] @ W3[512,512], heads=1 ----
  wsplit_kernel<<<dim3(F/32, F/32), 256, 0, stream>>>(W3, Bth, Btl, F, F);
  gemm_mfma<<<ggrid, 256, 0, stream>>>(feat, Bth, Btl, Hmat, N, F, F);
  attn_coef_kernel<1,512><<<N, 128, 0, stream>>>(Hmat, as3, ad3, al_s, al_d, Hb);
  alpha_kernel<1><<<N, 64, 0, stream>>>(al_s, al_d, rowptr, col, alphaE, denom);
  aggregate_kernel<1,false><<<N, 128, 0, stream>>>(Hb, alphaE, denom, rowptr, col, b3, out);
}

// Round 6
// 426.709 us; speedup vs baseline: 1.4326x; 1.0110x over previous
//
#include <hip/hip_runtime.h>

#define NSLOPE 0.2f

typedef __bf16 bf16x8 __attribute__((ext_vector_type(8)));
typedef __bf16 bf16x4 __attribute__((ext_vector_type(4)));
typedef float  f32x4  __attribute__((ext_vector_type(4)));

// ======================= CSR build (per-launch; ws is re-poisoned) ==========
__global__ void init_cnt_kernel(int* cnt, int n){
  int i = blockIdx.x*blockDim.x + threadIdx.x;
  if (i < n) cnt[i] = 1;                       // count the self-loop up front
}

__global__ void hist_kernel(const int* __restrict__ ei, int E, int* cnt){
  int e = blockIdx.x*blockDim.x + threadIdx.x;
  if (e < E) atomicAdd(&cnt[ei[E + e]], 1);    // dst row of edge_index
}

// single-block scan, wave-shuffle based (4 barriers per 1024-chunk)
__global__ void scan_kernel(const int* __restrict__ cnt, int* __restrict__ rowptr,
                            int* __restrict__ cursor, int n){
  __shared__ int wsum[16];
  __shared__ int carry, chunk_total;
  int t = threadIdx.x, lane = t & 63, wid = t >> 6;
  if (t == 0) carry = 0;
  __syncthreads();
  for (int base = 0; base < n; base += 1024){
    int idx = base + t;
    int v = (idx < n) ? cnt[idx] : 0;
    int inc = v;
#pragma unroll
    for (int off = 1; off < 64; off <<= 1){
      int u = __shfl_up(inc, off);
      if (lane >= off) inc += u;
    }
    if (lane == 63) wsum[wid] = inc;
    __syncthreads();
    if (t == 0){
      int s = 0;
#pragma unroll
      for (int i = 0; i < 16; i++){ int x = wsum[i]; wsum[i] = s; s += x; }
      chunk_total = s;
    }
    __syncthreads();
    int excl = carry + wsum[wid] + inc - v;
    if (idx < n){ rowptr[idx] = excl; cursor[idx] = excl; }
    __syncthreads();
    if (t == 0) carry += chunk_total;
    __syncthreads();
  }
  if (t == 0) rowptr[n] = carry;
}

__global__ void fill_kernel(const int* __restrict__ ei, int E, int n,
                            int* cursor, int* __restrict__ col){
  int i = blockIdx.x*blockDim.x + threadIdx.x;
  if (i < E){
    int s = ei[i], d = ei[E + i];
    int slot = atomicAdd(&cursor[d], 1);
    col[slot] = s;
  } else if (i < E + n){
    int v = i - E;                             // self loop (v -> v)
    int slot = atomicAdd(&cursor[v], 1);
    col[slot] = v;
  }
}

// ============ W [K][Nc] fp32 -> Bt_hi/Bt_lo [Nc][K] bf16 (split) ============
__global__ __launch_bounds__(256) void wsplit_kernel(
    const float* __restrict__ W, __bf16* __restrict__ Bthi,
    __bf16* __restrict__ Btlo, int K, int Nc){
  __shared__ float hi_s[32][33], lo_s[32][33];
  int tx = threadIdx.x & 31, ty = threadIdx.x >> 5;   // 32 x 8
  int k0 = blockIdx.x * 32, n0 = blockIdx.y * 32;
#pragma unroll
  for (int i = 0; i < 4; i++){
    int r = ty + i*8;
    float v = W[(size_t)(k0 + r)*Nc + n0 + tx];
    float h = (float)(__bf16)v;
    hi_s[r][tx] = h;
    lo_s[r][tx] = v - h;
  }
  __syncthreads();
#pragma unroll
  for (int i = 0; i < 4; i++){
    int n = ty + i*8;
    Bthi[(size_t)(n0 + n)*K + k0 + tx] = (__bf16)hi_s[tx][n];
    Btlo[(size_t)(n0 + n)*K + k0 + tx] = (__bf16)lo_s[tx][n];
  }
}

// ============ x [N][K] fp32 -> hi/lo bf16 (row-major, same layout) ==========
__global__ __launch_bounds__(256) void split_kernel(
    const float* __restrict__ X, __bf16* __restrict__ Xhi,
    __bf16* __restrict__ Xlo, int total){
  int i = (blockIdx.x*256 + threadIdx.x)*4;
  if (i < total){
    float4 v = *(const float4*)(X + i);
    float f[4] = {v.x, v.y, v.z, v.w};
    bf16x4 h, l;
#pragma unroll
    for (int u = 0; u < 4; u++){
      __bf16 hh = (__bf16)f[u];
      h[u] = hh;
      l[u] = (__bf16)(f[u] - (float)hh);
    }
    *(bf16x4*)(Xhi + i) = h;
    *(bf16x4*)(Xlo + i) = l;
  }
}

// ========== split-bf16 MFMA GEMM, pre-split A and B =========================
// C = Ahi*Bhi + Ahi*Blo + Alo*Bhi.  64x64 tile, 128 thr = 2 waves, BK=32.
// LDS fragment-major swizzle: chunk(iblk,q,mm) at idx iblk*64+q*16+mm (16B) ->
// fragment reads are base+lane*16 (conflict-free); staging writes likewise.
// Double-buffered, ONE barrier per K-iteration; global prefetch into regs.
__global__ __launch_bounds__(128) void gemm_mfma(
    const __bf16* __restrict__ Ahi, const __bf16* __restrict__ Alo,
    const __bf16* __restrict__ Bthi, const __bf16* __restrict__ Btlo,
    float* __restrict__ C, int M, int Nc, int K){
  __shared__ uint4 lds[2][4][256];   // [buf][Ah,Al,Bh,Bl][chunk] = 32 KiB
  int t  = threadIdx.x;
  int bm = blockIdx.x * 64, bn = blockIdx.y * 64;
  int lane = t & 63, w = t >> 6;
  int mm = lane & 15, q = lane >> 4;

  // staging chunk ids: m0 = t, m1 = t+128; chunk m -> row r=m>>2, khalf q=m&3
  const int r0 = t >> 2,        q0 = t & 3;
  const int r1 = (t + 128) >> 2, q1 = t & 3;
  const int di0 = ((t >> 6) << 6) | ((t & 3) << 4) | ((t >> 2) & 15);
  const int di1 = di0 + 128;
  const bool a0ok_base = true; // predicates computed per use below

  f32x4 acc[4][2];
#pragma unroll
  for (int i = 0; i < 4; i++)
#pragma unroll
    for (int j = 0; j < 2; j++)
#pragma unroll
      for (int r = 0; r < 4; r++) acc[i][j][r] = 0.f;

  const uint4 zero4 = make_uint4(0,0,0,0);
  uint4 pAh0, pAh1, pAl0, pAl1, pBh0, pBh1, pBl0, pBl1;

  // ---- prefetch tile 0 ----
  {
    int k0 = 0;
    bool ok0 = (bm + r0) < M, ok1 = (bm + r1) < M;
    const uint4* ah0 = (const uint4*)(Ahi + (size_t)(bm + r0)*K + k0 + q0*8);
    const uint4* ah1 = (const uint4*)(Ahi + (size_t)(bm + r1)*K + k0 + q1*8);
    const uint4* al0 = (const uint4*)(Alo + (size_t)(bm + r0)*K + k0 + q0*8);
    const uint4* al1 = (const uint4*)(Alo + (size_t)(bm + r1)*K + k0 + q1*8);
    pAh0 = ok0 ? *ah0 : zero4;  pAh1 = ok1 ? *ah1 : zero4;
    pAl0 = ok0 ? *al0 : zero4;  pAl1 = ok1 ? *al1 : zero4;
    pBh0 = *(const uint4*)(Bthi + (size_t)(bn + r0)*K + k0 + q0*8);
    pBh1 = *(const uint4*)(Bthi + (size_t)(bn + r1)*K + k0 + q1*8);
    pBl0 = *(const uint4*)(Btlo + (size_t)(bn + r0)*K + k0 + q0*8);
    pBl1 = *(const uint4*)(Btlo + (size_t)(bn + r1)*K + k0 + q1*8);
  }
  lds[0][0][di0] = pAh0; lds[0][0][di1] = pAh1;
  lds[0][1][di0] = pAl0; lds[0][1][di1] = pAl1;
  lds[0][2][di0] = pBh0; lds[0][2][di1] = pBh1;
  lds[0][3][di0] = pBl0; lds[0][3][di1] = pBl1;
  __syncthreads();

  const int niter = K >> 5;
  int b = 0;
  const int fa = q*16 + mm;
  for (int it = 0; it < niter; it++){
    if (it + 1 < niter){
      int k0 = (it + 1) << 5;
      bool ok0 = (bm + r0) < M, ok1 = (bm + r1) < M;
      const uint4* ah0 = (const uint4*)(Ahi + (size_t)(bm + r0)*K + k0 + q0*8);
      const uint4* ah1 = (const uint4*)(Ahi + (size_t)(bm + r1)*K + k0 + q1*8);
      const uint4* al0 = (const uint4*)(Alo + (size_t)(bm + r0)*K + k0 + q0*8);
      const uint4* al1 = (const uint4*)(Alo + (size_t)(bm + r1)*K + k0 + q1*8);
      pAh0 = ok0 ? *ah0 : zero4;  pAh1 = ok1 ? *ah1 : zero4;
      pAl0 = ok0 ? *al0 : zero4;  pAl1 = ok1 ? *al1 : zero4;
      pBh0 = *(const uint4*)(Bthi + (size_t)(bn + r0)*K + k0 + q0*8);
      pBh1 = *(const uint4*)(Bthi + (size_t)(bn + r1)*K + k0 + q1*8);
      pBl0 = *(const uint4*)(Btlo + (size_t)(bn + r0)*K + k0 + q0*8);
      pBl1 = *(const uint4*)(Btlo + (size_t)(bn + r1)*K + k0 + q1*8);
    }
    // ---- fragments from lds[b] ----
    bf16x8 a_h[4], a_l[4], b_h[2], b_l[2];
#pragma unroll
    for (int i = 0; i < 4; i++){
      a_h[i] = *(bf16x8*)&lds[b][0][i*64 + fa];
      a_l[i] = *(bf16x8*)&lds[b][1][i*64 + fa];
    }
#pragma unroll
    for (int jj = 0; jj < 2; jj++){
      b_h[jj] = *(bf16x8*)&lds[b][2][(w*2 + jj)*64 + fa];
      b_l[jj] = *(bf16x8*)&lds[b][3][(w*2 + jj)*64 + fa];
    }
#pragma unroll
    for (int i = 0; i < 4; i++)
#pragma unroll
      for (int jj = 0; jj < 2; jj++){
        acc[i][jj] = __builtin_amdgcn_mfma_f32_16x16x32_bf16(a_h[i], b_h[jj], acc[i][jj], 0, 0, 0);
        acc[i][jj] = __builtin_amdgcn_mfma_f32_16x16x32_bf16(a_h[i], b_l[jj], acc[i][jj], 0, 0, 0);
        acc[i][jj] = __builtin_amdgcn_mfma_f32_16x16x32_bf16(a_l[i], b_h[jj], acc[i][jj], 0, 0, 0);
      }
    if (it + 1 < niter){
      int nb = b ^ 1;
      lds[nb][0][di0] = pAh0; lds[nb][0][di1] = pAh1;
      lds[nb][1][di0] = pAl0; lds[nb][1][di1] = pAl1;
      lds[nb][2][di0] = pBh0; lds[nb][2][di1] = pBh1;
      lds[nb][3][di0] = pBl0; lds[nb][3][di1] = pBl1;
    }
    __syncthreads();
    b ^= 1;
  }

  // ---- store: reg r -> row = q*4 + r, col = mm ----
#pragma unroll
  for (int i = 0; i < 4; i++){
#pragma unroll
    for (int jj = 0; jj < 2; jj++){
      int colc = bn + w*32 + jj*16 + mm;
#pragma unroll
      for (int r = 0; r < 4; r++){
        int row = bm + i*16 + q*4 + r;
        if (row < M) C[(size_t)row*Nc + colc] = acc[i][jj][r];
      }
    }
  }
}

// ===== attention coefficients + bf16 copy of H for the gather ==============
template<int H, int CH>
__global__ __launch_bounds__(128) void attn_coef_kernel(
    const float* __restrict__ Hm, const float* __restrict__ asrc,
    const float* __restrict__ adst, float* __restrict__ al_s,
    float* __restrict__ al_d, __bf16* __restrict__ Hb){
  int b = blockIdx.x;                 // n*H + h
  int n = b / H, h = b % H;
  const float* row = Hm + (size_t)n*(H*CH) + (size_t)h*CH;
  int t = threadIdx.x;
  float ss = 0.f, sd = 0.f;
  for (int c = t; c < CH; c += 128){
    float v = row[c];
    Hb[(size_t)b*CH + c] = (__bf16)v;   // same flat layout as Hm
    ss += v * asrc[h*CH + c];
    sd += v * adst[h*CH + c];
  }
#pragma unroll
  for (int off = 32; off > 0; off >>= 1){
    ss += __shfl_down(ss, off);
    sd += __shfl_down(sd, off);
  }
  __shared__ float r0[2], r1[2];
  int wave = t >> 6, lane = t & 63;
  if (lane == 0){ r0[wave] = ss; r1[wave] = sd; }
  __syncthreads();
  if (t == 0){ al_s[b] = r0[0] + r0[1]; al_d[b] = r1[0] + r1[1]; }
}

// ========== per-dst softmax: one WAVE per node, shuffle-only ================
template<int H>
__global__ __launch_bounds__(64) void alpha_kernel(
    const float* __restrict__ al_s, const float* __restrict__ al_d,
    const int* __restrict__ rowptr, const int* __restrict__ col,
    float* __restrict__ alphaE, float* __restrict__ denom){
  int d = blockIdx.x;
  int lane = threadIdx.x;              // 0..63
  int start = rowptr[d], end = rowptr[d + 1];

  float ald[H];
#pragma unroll
  for (int h = 0; h < H; h++) ald[h] = al_d[(size_t)d*H + h];

  float mx[H];
#pragma unroll
  for (int h = 0; h < H; h++) mx[h] = -1e30f;
  for (int e = start + lane; e < end; e += 64){
    int s = col[e];
#pragma unroll
    for (int h = 0; h < H; h++){
      float v = al_s[(size_t)s*H + h] + ald[h];
      v = (v > 0.f) ? v : NSLOPE * v;
      mx[h] = fmaxf(mx[h], v);
    }
  }
#pragma unroll
  for (int h = 0; h < H; h++)
#pragma unroll
    for (int off = 32; off > 0; off >>= 1)
      mx[h] = fmaxf(mx[h], __shfl_xor(mx[h], off));

  float sm[H] = {};
  for (int e = start + lane; e < end; e += 64){
    int s = col[e];
#pragma unroll
    for (int h = 0; h < H; h++){
      float v = al_s[(size_t)s*H + h] + ald[h];
      v = (v > 0.f) ? v : NSLOPE * v;
      float ev = __expf(v - mx[h]);
      alphaE[(size_t)e*H + h] = ev;
      sm[h] += ev;
    }
  }
#pragma unroll
  for (int h = 0; h < H; h++)
#pragma unroll
    for (int off = 32; off > 0; off >>= 1)
      sm[h] += __shfl_xor(sm[h], off);
  if (lane == 0){
#pragma unroll
    for (int h = 0; h < H; h++) denom[(size_t)d*H + h] = sm[h];
  }
}

// ====== weighted gather from bf16 rows ======================================
// MODE 0: fp32 out, no ReLU (layer 3).  MODE 1: ReLU + bf16 hi/lo out.
template<int H, int MODE>
__global__ __launch_bounds__(128) void aggregate_kernel(
    const __bf16* __restrict__ Hb, const float* __restrict__ alphaE,
    const float* __restrict__ denom, const int* __restrict__ rowptr,
    const int* __restrict__ col, const float* __restrict__ bias,
    float* __restrict__ outF, __bf16* __restrict__ fhi,
    __bf16* __restrict__ flo){
  __shared__ int   src_lds[64];
  __shared__ float a_lds[64 * H];
  __shared__ float part[512];

  int d = blockIdx.x;
  int t = threadIdx.x;
  int g = t >> 6, lane = t & 63;
  int start = rowptr[d], end = rowptr[d + 1];
  const int hh = (lane * H) >> 6;              // head of lane's 8 channels
  const bf16x8* __restrict__ Hb8 = (const bf16x8*)Hb;   // row stride = 64

  float a0[8] = {};
  float a1[8] = {};
  for (int c0 = start; c0 < end; c0 += 64){
    int cnt = min(64, end - c0);
    if (t < cnt){
      src_lds[t] = col[c0 + t];
#pragma unroll
      for (int h = 0; h < H; h++)
        a_lds[t*H + h] = alphaE[(size_t)(c0 + t)*H + h];
    }
    __syncthreads();
    int i = g;
    for (; i + 2 < cnt; i += 4){
      int s0 = src_lds[i], s1 = src_lds[i + 2];
      float e0 = a_lds[i*H + hh], e1 = a_lds[(i + 2)*H + hh];
      bf16x8 v0 = Hb8[(size_t)s0*64 + lane];
      bf16x8 v1 = Hb8[(size_t)s1*64 + lane];
#pragma unroll
      for (int u = 0; u < 8; u++){
        a0[u] += e0 * (float)v0[u];
        a1[u] += e1 * (float)v1[u];
      }
    }
    for (; i < cnt; i += 2){
      int s0 = src_lds[i];
      float e0 = a_lds[i*H + hh];
      bf16x8 v0 = Hb8[(size_t)s0*64 + lane];
#pragma unroll
      for (int u = 0; u < 8; u++) a0[u] += e0 * (float)v0[u];
    }
    __syncthreads();
  }

  if (g == 1){
#pragma unroll
    for (int u = 0; u < 8; u++) part[lane*8 + u] = a0[u] + a1[u];
  }
  __syncthreads();
  if (g == 0){
    float inv = 1.f / denom[(size_t)d*H + hh];
    float r[8];
#pragma unroll
    for (int u = 0; u < 8; u++){
      float v = (a0[u] + a1[u] + part[lane*8 + u]) * inv + bias[lane*8 + u];
      if (MODE == 1) v = fmaxf(v, 0.f);
      r[u] = v;
    }
    if (MODE == 1){
      bf16x8 hv, lv;
#pragma unroll
      for (int u = 0; u < 8; u++){
        __bf16 h = (__bf16)r[u];
        hv[u] = h;
        lv[u] = (__bf16)(r[u] - (float)h);
      }
      *(bf16x8*)(fhi + (size_t)d*512 + lane*8) = hv;
      *(bf16x8*)(flo + (size_t)d*512 + lane*8) = lv;
    } else {
      float4* op = (float4*)(outF + (size_t)d*512 + lane*8);
      op[0] = make_float4(r[0], r[1], r[2], r[3]);
      op[1] = make_float4(r[4], r[5], r[6], r[7]);
    }
  }
}

// =========================== launch =========================================
extern "C" void kernel_launch(void* const* d_in, const int* in_sizes, int n_in,
                              void* d_out, int out_size, void* d_ws, size_t ws_size,
                              hipStream_t stream){
  const float* x   = (const float*)d_in[0];
  const int*   ei  = (const int*)  d_in[1];
  const float* W1  = (const float*)d_in[2];
  const float* as1 = (const float*)d_in[3];
  const float* ad1 = (const float*)d_in[4];
  const float* b1  = (const float*)d_in[5];
  const float* W2  = (const float*)d_in[6];
  const float* as2 = (const float*)d_in[7];
  const float* ad2 = (const float*)d_in[8];
  const float* b2  = (const float*)d_in[9];
  const float* W3  = (const float*)d_in[10];
  const float* as3 = (const float*)d_in[11];
  const float* ad3 = (const float*)d_in[12];
  const float* b3  = (const float*)d_in[13];
  float* out = (float*)d_out;

  const int N = in_sizes[0] / 128;   // 10000
  const int E = in_sizes[1] / 2;     // 320000
  const int F = 512;
  const int Etot = E + N;

  // workspace carve-up (same footprint as R4: feat fp32 slot now holds hi+lo)
  float*  Hmat   = (float*)d_ws;                      // N*512 fp32
  __bf16* feat_hi= (__bf16*)(Hmat + (size_t)N*F);     // N*512 bf16
  __bf16* feat_lo= feat_hi + (size_t)N*F;             // N*512 bf16
  float*  al_s   = (float*)(feat_lo + (size_t)N*F);   // N*4
  float*  al_d   = al_s + (size_t)N*4;                // N*4
  float*  alphaE = al_d + (size_t)N*4;                // (E+N)*4
  float*  denom  = alphaE + (size_t)Etot*4;           // N*4
  int*    cnt    = (int*)(denom + (size_t)N*4);       // N
  int*    rowptr = cnt + N;                           // N+1
  int*    cursor = rowptr + N + 1;                    // N
  int*    col    = cursor + N;                        // E+N
  uintptr_t p  = (uintptr_t)(col + Etot);
  p = (p + 15) & ~(uintptr_t)15;
  __bf16* Bth = (__bf16*)p;                           // 512*512 bf16
  __bf16* Btl = Bth + 512*512;                        // 512*512 bf16
  __bf16* Hb  = Btl + 512*512;                        // N*512 bf16 (gather)
  // x hi/lo (N*128 bf16 each = 5.12 MB) aliases alphaE region (5.28 MB):
  // consumed by layer-1 gemm BEFORE alpha_kernel first writes alphaE.
  __bf16* Xhi = (__bf16*)alphaE;
  __bf16* Xlo = Xhi + (size_t)N*128;

  // CSR by destination
  init_cnt_kernel<<<(N+255)/256, 256, 0, stream>>>(cnt, N);
  hist_kernel<<<(E+255)/256, 256, 0, stream>>>(ei, E, cnt);
  scan_kernel<<<1, 1024, 0, stream>>>(cnt, rowptr, cursor, N);
  fill_kernel<<<(E+N+255)/256, 256, 0, stream>>>(ei, E, N, cursor, col);

  dim3 ggrid((N + 63)/64, F/64);     // 157 x 8 = 1256 blocks

  // ---- layer 1: x[N,128] @ W1[128,512] ----
  split_kernel<<<(N*128/4 + 255)/256, 256, 0, stream>>>(x, Xhi, Xlo, N*128);
  wsplit_kernel<<<dim3(128/32, F/32), 256, 0, stream>>>(W1, Bth, Btl, 128, F);
  gemm_mfma<<<ggrid, 128, 0, stream>>>(Xhi, Xlo, Bth, Btl, Hmat, N, F, 128);
  attn_coef_kernel<4,128><<<N*4, 128, 0, stream>>>(Hmat, as1, ad1, al_s, al_d, Hb);
  alpha_kernel<4><<<N, 64, 0, stream>>>(al_s, al_d, rowptr, col, alphaE, denom);
  aggregate_kernel<4,1><<<N, 128, 0, stream>>>(Hb, alphaE, denom, rowptr, col, b1,
                                               (float*)nullptr, feat_hi, feat_lo);

  // ---- layer 2: feat[N,512] @ W2[512,512] ----
  wsplit_kernel<<<dim3(F/32, F/32), 256, 0, stream>>>(W2, Bth, Btl, F, F);
  gemm_mfma<<<ggrid, 128, 0, stream>>>(feat_hi, feat_lo, Bth, Btl, Hmat, N, F, F);
  attn_coef_kernel<4,128><<<N*4, 128, 0, stream>>>(Hmat, as2, ad2, al_s, al_d, Hb);
  alpha_kernel<4><<<N, 64, 0, stream>>>(al_s, al_d, rowptr, col, alphaE, denom);
  aggregate_kernel<4,1><<<N, 128, 0, stream>>>(Hb, alphaE, denom, rowptr, col, b2,
                                               (float*)nullptr, feat_hi, feat_lo);

  // ---- layer 3: feat[N,512] @ W3[512,512], heads=1 ----
  wsplit_kernel<<<dim3(F/32, F/32), 256, 0, stream>>>(W3, Bth, Btl, F, F);
  gemm_mfma<<<ggrid, 128, 0, stream>>>(feat_hi, feat_lo, Bth, Btl, Hmat, N, F, F);
  attn_coef_kernel<1,512><<<N, 128, 0, stream>>>(Hmat, as3, ad3, al_s, al_d, Hb);
  alpha_kernel<1><<<N, 64, 0, stream>>>(al_s, al_d, rowptr, col, alphaE, denom);
  aggregate_kernel<1,0><<<N, 128, 0, stream>>>(Hb, alphaE, denom, rowptr, col, b3,
                                               out, (__bf16*)nullptr, (__bf16*)nullptr);
}